// Round 2
// baseline (819.176 us; speedup 1.0000x reference)
//
#include <hip/hip_runtime.h>
#include <hip/hip_bf16.h>

typedef unsigned int u32;
typedef unsigned short u16;

// ---------- bf16 helpers (raw-bit, round-to-nearest-even on store) ----------
__device__ __forceinline__ float bflo(u32 p){ union{u32 u; float f;} v; v.u = p << 16; return v.f; }
__device__ __forceinline__ float bfhi(u32 p){ union{u32 u; float f;} v; v.u = p & 0xFFFF0000u; return v.f; }
__device__ __forceinline__ u16 f2bf(float f){
    union{float f; u32 u;} v; v.f = f;
    u32 r = (v.u + 0x7FFFu + ((v.u >> 16) & 1u)) >> 16;
    return (u16)r;
}
__device__ __forceinline__ u32 pack2(float a, float b){
    return ((u32)f2bf(a)) | (((u32)f2bf(b)) << 16);
}
// orderable-uint mapping for float atomicMax (init = 0 is below all finite floats)
__device__ __forceinline__ u32 f2ord(float f){
    union{float f; u32 u;} v; v.f = f;
    return (v.u & 0x80000000u) ? ~v.u : (v.u | 0x80000000u);
}
__device__ __forceinline__ float ord2f(u32 u){
    union{u32 u; float f;} v;
    v.u = (u & 0x80000000u) ? (u ^ 0x80000000u) : ~u;
    return v.f;
}

#define HH 16
#define CC 32
#define HC 512   // H*C
#define KIN 128

// ---------- K0: fused GEMM  x@[W_l | W_r | W_res]  (all fp32 in) ----------
// 8 rows per block, 256 threads, 2 output cols per thread.
// xl/xr written as packed bf16; xres fp32.
__global__ __launch_bounds__(256) void k_gemm(
    const float* __restrict__ x, const float* __restrict__ Wl, const float* __restrict__ Wr,
    const float* __restrict__ Wres, u16* __restrict__ xl, u16* __restrict__ xr,
    float* __restrict__ xres, int N)
{
    __shared__ float xs[8 * KIN];
    const int tid = threadIdx.x;
    const int row0 = blockIdx.x * 8;

    const float* xrow = x + (size_t)row0 * KIN;
    #pragma unroll
    for (int t = 0; t < 4; t++) {
        int idx = tid + t * 256;                 // 0..1023
        xs[idx] = xrow[idx];                     // N % 8 == 0: no partial blocks
    }
    __syncthreads();

    const float2* Wl2 = (const float2*)Wl;   // [128][256] col-pairs
    const float2* Wr2 = (const float2*)Wr;
    float aL0[8] = {0}, aL1[8] = {0}, aR0[8] = {0}, aR1[8] = {0};
    for (int k = 0; k < KIN; k++) {
        float2 wl = Wl2[k * 256 + tid];
        float2 wr = Wr2[k * 256 + tid];
        #pragma unroll
        for (int r = 0; r < 8; r++) {
            float xv = xs[r * KIN + k];
            aL0[r] += xv * wl.x; aL1[r] += xv * wl.y;
            aR0[r] += xv * wr.x; aR1[r] += xv * wr.y;
        }
    }
    u32* xl2 = (u32*)xl; u32* xr2 = (u32*)xr;
    #pragma unroll
    for (int r = 0; r < 8; r++) {
        xl2[(size_t)(row0 + r) * 256 + tid] = pack2(aL0[r], aL1[r]);
        xr2[(size_t)(row0 + r) * 256 + tid] = pack2(aR0[r], aR1[r]);
    }
    if (tid < 16) {   // residual projection: 32 cols = 16 col-pairs
        const float2* W2 = (const float2*)Wres;
        float c0[8] = {0}, c1[8] = {0};
        for (int k = 0; k < KIN; k++) {
            float2 w = W2[k * 16 + tid];
            #pragma unroll
            for (int r = 0; r < 8; r++) {
                float xv = xs[r * KIN + k];
                c0[r] += xv * w.x; c1[r] += xv * w.y;
            }
        }
        #pragma unroll
        for (int r = 0; r < 8; r++) {
            xres[(size_t)(row0 + r) * CC + 2 * tid]     = c0[r];
            xres[(size_t)(row0 + r) * CC + 2 * tid + 1] = c1[r];
        }
    }
}

// ---------- K1: per-edge attention scores + segment max ----------
// 1 wave per edge. lane -> 8 contiguous channels; head = lane>>2.
__global__ __launch_bounds__(256) void k_scores(
    const int* __restrict__ ei, const u16* __restrict__ xl, const u16* __restrict__ xr,
    const float* __restrict__ att, float* __restrict__ e_buf, u32* __restrict__ m_u,
    int E, int N)
{
    int gid = blockIdx.x * 256 + threadIdx.x;
    int edge = gid >> 6;
    int lane = gid & 63;
    if (edge >= E + N) return;
    int src, dst;
    if (edge < E) { src = ei[edge]; dst = ei[E + edge]; }
    else          { src = edge - E; dst = src; }

    uint4 a = ((const uint4*)(xl + (size_t)src * HC))[lane];
    uint4 b = ((const uint4*)(xr + (size_t)dst * HC))[lane];
    float4 w0 = ((const float4*)att)[lane * 2];
    float4 w1 = ((const float4*)att)[lane * 2 + 1];

    u32 pa[4] = {a.x, a.y, a.z, a.w};
    u32 pb[4] = {b.x, b.y, b.z, b.w};
    float wv[8] = {w0.x, w0.y, w0.z, w0.w, w1.x, w1.y, w1.z, w1.w};
    float sum = 0.f;
    #pragma unroll
    for (int q = 0; q < 4; q++) {
        float v0 = bflo(pa[q]) + bflo(pb[q]);
        float v1 = bfhi(pa[q]) + bfhi(pb[q]);
        v0 = v0 > 0.f ? v0 : 0.2f * v0;     // leaky_relu
        v1 = v1 > 0.f ? v1 : 0.2f * v1;
        sum += v0 * wv[2 * q] + v1 * wv[2 * q + 1];
    }
    sum += __shfl_xor(sum, 1);
    sum += __shfl_xor(sum, 2);
    if ((lane & 3) == 0) {
        int h = lane >> 2;
        e_buf[(size_t)edge * HH + h] = sum;
        atomicMax(&m_u[(size_t)dst * HH + h], f2ord(sum));
    }
}

// ---------- K2: exp(e - m[dst]) in place + segment sum ----------
__global__ __launch_bounds__(256) void k_expsum(
    const int* __restrict__ ei, float* __restrict__ e_buf, const u32* __restrict__ m_u,
    float* __restrict__ s, int E, int N)
{
    long long i = (long long)blockIdx.x * 256 + threadIdx.x;
    long long tot = (long long)(E + N) * HH;
    if (i >= tot) return;
    int edge = (int)(i >> 4);
    int h = (int)(i & 15);
    int dst = (edge < E) ? ei[E + edge] : edge - E;
    float m = ord2f(m_u[(size_t)dst * HH + h]);
    float ex = expf(e_buf[i] - m);
    e_buf[i] = ex;
    atomicAdd(&s[(size_t)dst * HH + h], ex);
}

// ---------- K3: alpha + head-reduced scatter into out_mean ----------
// 1 wave per edge. In-wave head reduction: lanes sharing (lane&3) hold the
// same channel block across 16 heads -> shfl_xor 4/8/16/32, lanes 0..3 atomically
// add 32 channel values into out_mean[dst][0..31].
__global__ __launch_bounds__(256) void k_alpha_agg(
    const int* __restrict__ ei, const u16* __restrict__ xl, const float* __restrict__ e_buf,
    const float* __restrict__ s, float* __restrict__ alpha_out, float* __restrict__ out_mean,
    int E, int N)
{
    int gid = blockIdx.x * 256 + threadIdx.x;
    int edge = gid >> 6;
    int lane = gid & 63;
    if (edge >= E + N) return;
    int src, dst;
    if (edge < E) { src = ei[edge]; dst = ei[E + edge]; }
    else          { src = edge - E; dst = src; }

    if (lane < 16) {
        float ex = e_buf[(size_t)edge * HH + lane];
        float al = ex / (s[(size_t)dst * HH + lane] + 1e-16f);
        alpha_out[(size_t)edge * HH + lane] = al;
    }
    int h = lane >> 2;
    float alpha = e_buf[(size_t)edge * HH + h] / (s[(size_t)dst * HH + h] + 1e-16f);

    uint4 a = ((const uint4*)(xl + (size_t)src * HC))[lane];
    u32 pa[4] = {a.x, a.y, a.z, a.w};
    float acc[8];
    #pragma unroll
    for (int q = 0; q < 4; q++) {
        acc[2 * q]     = bflo(pa[q]) * alpha;
        acc[2 * q + 1] = bfhi(pa[q]) * alpha;
    }
    // reduce over the 16 heads (lanes with equal lane&3)
    #pragma unroll
    for (int mres = 4; mres <= 32; mres <<= 1) {
        #pragma unroll
        for (int q = 0; q < 8; q++) acc[q] += __shfl_xor(acc[q], mres);
    }
    if (lane < 4) {
        float* dp = out_mean + (size_t)dst * CC + lane * 8;
        #pragma unroll
        for (int q = 0; q < 8; q++) atomicAdd(dp + q, acc[q]);
    }
}

// ---------- K4: head mean + bias + ReLU + residual ----------
__global__ __launch_bounds__(256) void k_final(
    const float* __restrict__ out_mean, const float* __restrict__ xres,
    const float* __restrict__ bias, float* __restrict__ x_out, int N)
{
    int i = blockIdx.x * 256 + threadIdx.x;
    if (i >= N * CC) return;
    int c = i & 31;
    float g = out_mean[i] * (1.f / 16.f) + bias[c];
    g = g > 0.f ? g : 0.f;
    x_out[i] = g + xres[i];
}

extern "C" void kernel_launch(void* const* d_in, const int* in_sizes, int n_in,
                              void* d_out, int out_size, void* d_ws, size_t ws_size,
                              hipStream_t stream)
{
    const int N = in_sizes[0] / KIN;   // 50000
    const int E = in_sizes[1] / 2;     // 400000
    const int Etot = E + N;

    const float* x    = (const float*)d_in[0];
    const int*   ei   = (const int*)d_in[1];
    const float* Wl   = (const float*)d_in[4];
    const float* Wr   = (const float*)d_in[5];
    const float* att  = (const float*)d_in[6];
    const float* bias = (const float*)d_in[7];
    const float* Wres = (const float*)d_in[8];

    char* ws = (char*)d_ws;
    u16*   xl       = (u16*)ws;   ws += (size_t)N * HC * 2;
    u16*   xr       = (u16*)ws;   ws += (size_t)N * HC * 2;
    float* e_buf    = (float*)ws; ws += (size_t)Etot * HH * 4;
    float* s        = (float*)ws; ws += (size_t)N * HH * 4;
    u32*   m_u      = (u32*)ws;   ws += (size_t)N * HH * 4;
    float* xres     = (float*)ws; ws += (size_t)N * CC * 4;
    float* out_mean = (float*)ws; ws += (size_t)N * CC * 4;

    float* x_out     = (float*)d_out;
    float* alpha_out = x_out + (size_t)N * CC;

    hipMemsetAsync(s,        0, (size_t)N * HH * 4, stream);
    hipMemsetAsync(m_u,      0, (size_t)N * HH * 4, stream);
    hipMemsetAsync(out_mean, 0, (size_t)N * CC * 4, stream);

    k_gemm<<<N / 8, 256, 0, stream>>>(x, Wl, Wr, Wres, xl, xr, xres, N);

    int waves_grid = (int)(((long long)Etot * 64 + 255) / 256);
    k_scores<<<waves_grid, 256, 0, stream>>>(ei, xl, xr, att, e_buf, m_u, E, N);

    int expsum_grid = (int)(((long long)Etot * HH + 255) / 256);
    k_expsum<<<expsum_grid, 256, 0, stream>>>(ei, e_buf, m_u, s, E, N);

    k_alpha_agg<<<waves_grid, 256, 0, stream>>>(ei, xl, e_buf, s, alpha_out, out_mean, E, N);

    k_final<<<(N * CC + 255) / 256, 256, 0, stream>>>(out_mean, xres, bias, x_out, N);
}

// Round 3
// 411.991 us; speedup vs baseline: 1.9883x; 1.9883x over previous
//
#include <hip/hip_runtime.h>
#include <hip/hip_bf16.h>

typedef unsigned int u32;
typedef unsigned short u16;

// ---------- bf16 helpers ----------
__device__ __forceinline__ float bflo(u32 p){ union{u32 u; float f;} v; v.u = p << 16; return v.f; }
__device__ __forceinline__ float bfhi(u32 p){ union{u32 u; float f;} v; v.u = p & 0xFFFF0000u; return v.f; }
__device__ __forceinline__ u16 f2bf(float f){
    union{float f; u32 u;} v; v.f = f;
    u32 r = (v.u + 0x7FFFu + ((v.u >> 16) & 1u)) >> 16;
    return (u16)r;
}
__device__ __forceinline__ u32 pack2(float a, float b){
    return ((u32)f2bf(a)) | (((u32)f2bf(b)) << 16);
}

#define HH 16
#define CC 32
#define HC 512   // H*C
#define KIN 128

// ---------- K0: fused GEMM  x@[W_l | W_r | W_res]  (fp32 in, bf16 xl/xr out) ----------
__global__ __launch_bounds__(256) void k_gemm(
    const float* __restrict__ x, const float* __restrict__ Wl, const float* __restrict__ Wr,
    const float* __restrict__ Wres, u16* __restrict__ xl, u16* __restrict__ xr,
    float* __restrict__ xres, int N)
{
    __shared__ float xs[8 * KIN];
    const int tid = threadIdx.x;
    const int row0 = blockIdx.x * 8;

    const float* xrow = x + (size_t)row0 * KIN;
    #pragma unroll
    for (int t = 0; t < 4; t++) {
        int idx = tid + t * 256;
        xs[idx] = xrow[idx];
    }
    __syncthreads();

    const float2* Wl2 = (const float2*)Wl;
    const float2* Wr2 = (const float2*)Wr;
    float aL0[8] = {0}, aL1[8] = {0}, aR0[8] = {0}, aR1[8] = {0};
    for (int k = 0; k < KIN; k++) {
        float2 wl = Wl2[k * 256 + tid];
        float2 wr = Wr2[k * 256 + tid];
        #pragma unroll
        for (int r = 0; r < 8; r++) {
            float xv = xs[r * KIN + k];
            aL0[r] += xv * wl.x; aL1[r] += xv * wl.y;
            aR0[r] += xv * wr.x; aR1[r] += xv * wr.y;
        }
    }
    u32* xl2 = (u32*)xl; u32* xr2 = (u32*)xr;
    #pragma unroll
    for (int r = 0; r < 8; r++) {
        xl2[(size_t)(row0 + r) * 256 + tid] = pack2(aL0[r], aL1[r]);
        xr2[(size_t)(row0 + r) * 256 + tid] = pack2(aR0[r], aR1[r]);
    }
    if (tid < 16) {
        const float2* W2 = (const float2*)Wres;
        float c0[8] = {0}, c1[8] = {0};
        for (int k = 0; k < KIN; k++) {
            float2 w = W2[k * 16 + tid];
            #pragma unroll
            for (int r = 0; r < 8; r++) {
                float xv = xs[r * KIN + k];
                c0[r] += xv * w.x; c1[r] += xv * w.y;
            }
        }
        #pragma unroll
        for (int r = 0; r < 8; r++) {
            xres[(size_t)(row0 + r) * CC + 2 * tid]     = c0[r];
            xres[(size_t)(row0 + r) * CC + 2 * tid + 1] = c1[r];
        }
    }
}

// ---------- CSR build ----------
__global__ __launch_bounds__(256) void k_count(
    const int* __restrict__ ei, int* __restrict__ counts, int E, int N)
{
    int e = blockIdx.x * 256 + threadIdx.x;
    if (e >= E + N) return;
    int dst = (e < E) ? ei[E + e] : e - E;
    atomicAdd(&counts[dst], 1);
}

__global__ __launch_bounds__(1024) void k_scan1(
    const int* __restrict__ counts, int* __restrict__ offs, int* __restrict__ partials, int N)
{
    __shared__ int sh[1024];
    int i = blockIdx.x * 1024 + threadIdx.x;
    int v = (i < N) ? counts[i] : 0;
    sh[threadIdx.x] = v;
    __syncthreads();
    for (int off = 1; off < 1024; off <<= 1) {
        int t = (threadIdx.x >= off) ? sh[threadIdx.x - off] : 0;
        __syncthreads();
        sh[threadIdx.x] += t;
        __syncthreads();
    }
    if (i < N) offs[i] = sh[threadIdx.x] - v;   // exclusive
    if (threadIdx.x == 1023) partials[blockIdx.x] = sh[1023];
}

__global__ void k_scan2(int* __restrict__ partials, int nb)
{
    if (threadIdx.x == 0 && blockIdx.x == 0) {
        int run = 0;
        for (int k = 0; k < nb; k++) { int t = partials[k]; partials[k] = run; run += t; }
    }
}

__global__ __launch_bounds__(1024) void k_scan3(
    int* __restrict__ offs, const int* __restrict__ partials, int* __restrict__ cursor, int N)
{
    int i = blockIdx.x * 1024 + threadIdx.x;
    if (i < N) {
        int o = offs[i] + partials[blockIdx.x];
        offs[i] = o;
        cursor[i] = o;
    }
}

__global__ __launch_bounds__(256) void k_scatter(
    const int* __restrict__ ei, int* __restrict__ cursor,
    int* __restrict__ src_sorted, int* __restrict__ eid_sorted, int E, int N)
{
    int e = blockIdx.x * 256 + threadIdx.x;
    if (e >= E + N) return;
    int src, dst;
    if (e < E) { src = ei[e]; dst = ei[E + e]; }
    else       { src = e - E; dst = src; }
    int pos = atomicAdd(&cursor[dst], 1);
    src_sorted[pos] = src;
    eid_sorted[pos] = e;
}

// ---------- K_fused: per-node online-softmax score + aggregate (1 wave / node) ----------
// lane -> 8 contiguous channels of head (lane>>2). xr row held in registers.
__global__ __launch_bounds__(256) void k_fused(
    const int* __restrict__ src_sorted, const int* __restrict__ eid_sorted,
    const int* __restrict__ offs, const int* __restrict__ counts,
    const u16* __restrict__ xl, const u16* __restrict__ xr, const float* __restrict__ att,
    float* __restrict__ e_buf, float* __restrict__ m_buf, float* __restrict__ s_buf,
    float* __restrict__ out_mean, int N)
{
    int wid = (blockIdx.x * 256 + threadIdx.x) >> 6;
    int lane = threadIdx.x & 63;
    if (wid >= N) return;
    const int node = wid;

    uint4 b = ((const uint4*)(xr + (size_t)node * HC))[lane];
    float xrv[8] = { bflo(b.x), bfhi(b.x), bflo(b.y), bfhi(b.y),
                     bflo(b.z), bfhi(b.z), bflo(b.w), bfhi(b.w) };
    float4 w0 = ((const float4*)att)[lane * 2];
    float4 w1 = ((const float4*)att)[lane * 2 + 1];
    float wv[8] = { w0.x, w0.y, w0.z, w0.w, w1.x, w1.y, w1.z, w1.w };

    float m = -3.402823466e38f, s = 0.f;
    float acc[8] = {0, 0, 0, 0, 0, 0, 0, 0};

    const int beg = offs[node];
    const int deg = counts[node];

    for (int base = 0; base < deg; base += 64) {
        int cnt = min(64, deg - base);
        int my_src = 0, my_eid = 0;
        if (lane < cnt) {
            my_src = src_sorted[beg + base + lane];
            my_eid = eid_sorted[beg + base + lane];
        }
        int s0 = __shfl(my_src, 0);
        uint4 a = ((const uint4*)(xl + (size_t)s0 * HC))[lane];
        for (int t = 0; t < cnt; t++) {
            uint4 ac = a;
            if (t + 1 < cnt) {   // prefetch next row
                int sn = __shfl(my_src, t + 1);
                a = ((const uint4*)(xl + (size_t)sn * HC))[lane];
            }
            float xv[8] = { bflo(ac.x), bfhi(ac.x), bflo(ac.y), bfhi(ac.y),
                            bflo(ac.z), bfhi(ac.z), bflo(ac.w), bfhi(ac.w) };
            float esum = 0.f;
            #pragma unroll
            for (int q = 0; q < 8; q++) {
                float v = xv[q] + xrv[q];
                v = v > 0.f ? v : 0.2f * v;      // leaky_relu
                esum += v * wv[q];
            }
            esum += __shfl_xor(esum, 1);
            esum += __shfl_xor(esum, 2);         // all 4 lanes of head group hold e

            int eid = __shfl(my_eid, t);
            if ((lane & 3) == 0)
                e_buf[(size_t)eid * HH + (lane >> 2)] = esum;

            float mn = fmaxf(m, esum);
            float sc = __expf(m - mn);
            float p  = __expf(esum - mn);
            s = s * sc + p;
            m = mn;
            #pragma unroll
            for (int q = 0; q < 8; q++) acc[q] = acc[q] * sc + p * xv[q];
        }
    }

    if ((lane & 3) == 0) {
        m_buf[(size_t)node * HH + (lane >> 2)] = m;
        s_buf[(size_t)node * HH + (lane >> 2)] = s;
    }
    float inv = 1.f / (s + 1e-16f);
    #pragma unroll
    for (int q = 0; q < 8; q++) acc[q] *= inv;
    // reduce across the 16 heads (lanes sharing lane&3)
    #pragma unroll
    for (int st = 4; st <= 32; st <<= 1) {
        #pragma unroll
        for (int q = 0; q < 8; q++) acc[q] += __shfl_xor(acc[q], st);
    }
    if (lane < 4) {
        float* dp = out_mean + (size_t)node * CC + lane * 8;
        #pragma unroll
        for (int q = 0; q < 8; q++) dp[q] = acc[q];
    }
}

// ---------- K_alpha: alpha = exp(e - m[dst]) / s[dst] ----------
__global__ __launch_bounds__(256) void k_alpha(
    const int* __restrict__ ei, const float* __restrict__ e_buf,
    const float* __restrict__ m_buf, const float* __restrict__ s_buf,
    float* __restrict__ alpha_out, int E, int N)
{
    long long i = (long long)blockIdx.x * 256 + threadIdx.x;
    long long tot = (long long)(E + N) * HH;
    if (i >= tot) return;
    int edge = (int)(i >> 4);
    int h = (int)(i & 15);
    int dst = (edge < E) ? ei[E + edge] : edge - E;
    float m = m_buf[(size_t)dst * HH + h];
    float s = s_buf[(size_t)dst * HH + h];
    alpha_out[i] = __expf(e_buf[i] - m) / (s + 1e-16f);
}

// ---------- K_final: head mean + bias + ReLU + residual ----------
__global__ __launch_bounds__(256) void k_final(
    const float* __restrict__ out_mean, const float* __restrict__ xres,
    const float* __restrict__ bias, float* __restrict__ x_out, int N)
{
    int i = blockIdx.x * 256 + threadIdx.x;
    if (i >= N * CC) return;
    int c = i & 31;
    float g = out_mean[i] * (1.f / 16.f) + bias[c];
    g = g > 0.f ? g : 0.f;
    x_out[i] = g + xres[i];
}

extern "C" void kernel_launch(void* const* d_in, const int* in_sizes, int n_in,
                              void* d_out, int out_size, void* d_ws, size_t ws_size,
                              hipStream_t stream)
{
    const int N = in_sizes[0] / KIN;   // 50000
    const int E = in_sizes[1] / 2;     // 400000
    const int Etot = E + N;

    const float* x    = (const float*)d_in[0];
    const int*   ei   = (const int*)d_in[1];
    const float* Wl   = (const float*)d_in[4];
    const float* Wr   = (const float*)d_in[5];
    const float* att  = (const float*)d_in[6];
    const float* bias = (const float*)d_in[7];
    const float* Wres = (const float*)d_in[8];

    char* ws = (char*)d_ws;
    u16*   xl         = (u16*)ws;   ws += (size_t)N * HC * 2;
    u16*   xr         = (u16*)ws;   ws += (size_t)N * HC * 2;
    float* e_buf      = (float*)ws; ws += (size_t)Etot * HH * 4;
    float* m_buf      = (float*)ws; ws += (size_t)N * HH * 4;
    float* s_buf      = (float*)ws; ws += (size_t)N * HH * 4;
    float* xres       = (float*)ws; ws += (size_t)N * CC * 4;
    float* out_mean   = (float*)ws; ws += (size_t)N * CC * 4;
    int*   counts     = (int*)ws;   ws += (size_t)N * 4;
    int*   offs       = (int*)ws;   ws += (size_t)N * 4;
    int*   cursor     = (int*)ws;   ws += (size_t)N * 4;
    int*   partials   = (int*)ws;   ws += 256;
    int*   src_sorted = (int*)ws;   ws += (size_t)Etot * 4;
    int*   eid_sorted = (int*)ws;   ws += (size_t)Etot * 4;

    float* x_out     = (float*)d_out;
    float* alpha_out = x_out + (size_t)N * CC;

    hipMemsetAsync(counts, 0, (size_t)N * 4, stream);

    k_gemm<<<N / 8, 256, 0, stream>>>(x, Wl, Wr, Wres, xl, xr, xres, N);

    int eg = (Etot + 255) / 256;
    k_count<<<eg, 256, 0, stream>>>(ei, counts, E, N);

    int nb = (N + 1023) / 1024;
    k_scan1<<<nb, 1024, 0, stream>>>(counts, offs, partials, N);
    k_scan2<<<1, 64, 0, stream>>>(partials, nb);
    k_scan3<<<nb, 1024, 0, stream>>>(offs, partials, cursor, N);

    k_scatter<<<eg, 256, 0, stream>>>(ei, cursor, src_sorted, eid_sorted, E, N);

    k_fused<<<(N * 64 + 255) / 256, 256, 0, stream>>>(
        src_sorted, eid_sorted, offs, counts, xl, xr, att,
        e_buf, m_buf, s_buf, out_mean, N);

    int ag = (int)(((long long)Etot * HH + 255) / 256);
    k_alpha<<<ag, 256, 0, stream>>>(ei, e_buf, m_buf, s_buf, alpha_out, E, N);

    k_final<<<(N * CC + 255) / 256, 256, 0, stream>>>(out_mean, xres, bias, x_out, N);
}

// Round 4
// 258.700 us; speedup vs baseline: 3.1665x; 1.5925x over previous
//
#include <hip/hip_runtime.h>
#include <hip/hip_bf16.h>

typedef unsigned int u32;
typedef unsigned short u16;

typedef __attribute__((ext_vector_type(8))) short bf16x8;
typedef __attribute__((ext_vector_type(4))) float f32x4;

// ---------- bf16 helpers ----------
__device__ __forceinline__ float bflo(u32 p){ union{u32 u; float f;} v; v.u = p << 16; return v.f; }
__device__ __forceinline__ float bfhi(u32 p){ union{u32 u; float f;} v; v.u = p & 0xFFFF0000u; return v.f; }
__device__ __forceinline__ u16 f2bf(float f){
    union{float f; u32 u;} v; v.f = f;
    u32 r = (v.u + 0x7FFFu + ((v.u >> 16) & 1u)) >> 16;
    return (u16)r;
}
__device__ __forceinline__ u32 pack2(float a, float b){
    return ((u32)f2bf(a)) | (((u32)f2bf(b)) << 16);
}

#define HH 16
#define CC 32
#define HC 512   // H*C
#define KIN 128
#define CT 1056  // 512 + 512 + 32 output cols

// ---------- K_xconv: x fp32 -> bf16 (packed) ----------
__global__ __launch_bounds__(256) void k_xconv(
    const float* __restrict__ x, u16* __restrict__ xb, int total)
{
    int t = blockIdx.x * 256 + threadIdx.x;   // one thread = 8 floats
    if (t * 8 >= total) return;
    const float4* src = (const float4*)(x + (size_t)t * 8);
    float4 a = src[0], b = src[1];
    uint4 o;
    o.x = pack2(a.x, a.y); o.y = pack2(a.z, a.w);
    o.z = pack2(b.x, b.y); o.w = pack2(b.z, b.w);
    ((uint4*)xb)[t] = o;
}

// ---------- K_wconv: W fp32 [128][cols] -> wbt bf16 [1056][128] (transposed) ----------
__global__ __launch_bounds__(128) void k_wconv(
    const float* __restrict__ Wl, const float* __restrict__ Wr,
    const float* __restrict__ Wres, u16* __restrict__ wbt)
{
    int c = blockIdx.x;        // 0..1055
    int k = threadIdx.x;       // 0..127
    float v;
    if (c < 512)       v = Wl[(size_t)k * 512 + c];
    else if (c < 1024) v = Wr[(size_t)k * 512 + (c - 512)];
    else               v = Wres[(size_t)k * 32 + (c - 1024)];
    wbt[(size_t)c * 128 + k] = f2bf(v);
}

// ---------- K_mfma: [M,128] x [128,1056] via mfma_f32_16x16x32_bf16 ----------
// Block: 128 rows x 128 cols, 4 waves (32 rows each). A in LDS, 16B-chunk
// XOR swizzle (chunk ^= row&7) for conflict-free ds_read_b128 fragments.
__global__ __launch_bounds__(256) void k_mfma(
    const u16* __restrict__ xb, const u16* __restrict__ wbt,
    u16* __restrict__ xl, u16* __restrict__ xr, float* __restrict__ xres, int N)
{
    __shared__ u16 As[128 * 128];   // 32 KB
    const int tid = threadIdx.x;
    const int wave = tid >> 6, lane = tid & 63;
    const int row0 = blockIdx.x * 128;
    const int col0 = blockIdx.y * 128;
    const int nct = (blockIdx.y == 8) ? 2 : 8;   // y==8 -> xres (32 cols)

    // stage A: thread i handles 16B chunk (row i>>4, chunk i&15)
    uint4 zero = {0, 0, 0, 0};
    #pragma unroll
    for (int it = 0; it < 8; it++) {
        int i = tid + it * 256;          // 0..2047
        int r = i >> 4, ch = i & 15;
        int grow = row0 + r;
        uint4 v = (grow < N) ? ((const uint4*)(xb + (size_t)grow * KIN))[ch] : zero;
        *(uint4*)(As + r * 128 + ((ch ^ (r & 7)) * 8)) = v;
    }
    __syncthreads();

    // A fragments: lane&15 -> row, (lane>>4)*8 -> k offset within K=32 step
    bf16x8 afrag[2][4];
    #pragma unroll
    for (int mt = 0; mt < 2; mt++) {
        #pragma unroll
        for (int kk = 0; kk < 4; kk++) {
            int r = wave * 32 + mt * 16 + (lane & 15);
            int chunk = (kk * 4 + (lane >> 4)) ^ (r & 7);
            afrag[mt][kk] = *(const bf16x8*)(As + r * 128 + chunk * 8);
        }
    }

    #pragma unroll
    for (int nt = 0; nt < 8; nt++) {
        if (nt < nct) {
            int col = col0 + nt * 16 + (lane & 15);
            const uint4* bp = (const uint4*)(wbt + (size_t)col * KIN);
            bf16x8 bfrag[4];
            #pragma unroll
            for (int kk = 0; kk < 4; kk++) {
                union { uint4 u; bf16x8 v; } cv;
                cv.u = bp[kk * 4 + (lane >> 4)];
                bfrag[kk] = cv.v;
            }
            f32x4 acc0 = {0, 0, 0, 0}, acc1 = {0, 0, 0, 0};
            #pragma unroll
            for (int kk = 0; kk < 4; kk++) {
                acc0 = __builtin_amdgcn_mfma_f32_16x16x32_bf16(afrag[0][kk], bfrag[kk], acc0, 0, 0, 0);
                acc1 = __builtin_amdgcn_mfma_f32_16x16x32_bf16(afrag[1][kk], bfrag[kk], acc1, 0, 0, 0);
            }
            // C/D: col = lane&15, row = (lane>>4)*4 + j
            int c_all = col0 + nt * 16 + (lane & 15);
            #pragma unroll
            for (int mt = 0; mt < 2; mt++) {
                f32x4 a = (mt == 0) ? acc0 : acc1;
                int rb = row0 + wave * 32 + mt * 16 + (lane >> 4) * 4;
                #pragma unroll
                for (int j = 0; j < 4; j++) {
                    int grow = rb + j;
                    if (grow < N) {
                        float v = a[j];
                        if (c_all < 512)       xl[(size_t)grow * HC + c_all] = f2bf(v);
                        else if (c_all < 1024) xr[(size_t)grow * HC + (c_all - 512)] = f2bf(v);
                        else                   xres[(size_t)grow * CC + (c_all - 1024)] = v;
                    }
                }
            }
        }
    }
}

// ---------- CSR build ----------
__global__ __launch_bounds__(256) void k_count(
    const int* __restrict__ ei, int* __restrict__ counts, int E, int N)
{
    int e = blockIdx.x * 256 + threadIdx.x;
    if (e >= E + N) return;
    int dst = (e < E) ? ei[E + e] : e - E;
    atomicAdd(&counts[dst], 1);
}

__global__ __launch_bounds__(1024) void k_scan1(
    const int* __restrict__ counts, int* __restrict__ offs, int* __restrict__ partials, int N)
{
    __shared__ int sh[1024];
    int i = blockIdx.x * 1024 + threadIdx.x;
    int v = (i < N) ? counts[i] : 0;
    sh[threadIdx.x] = v;
    __syncthreads();
    for (int off = 1; off < 1024; off <<= 1) {
        int t = (threadIdx.x >= off) ? sh[threadIdx.x - off] : 0;
        __syncthreads();
        sh[threadIdx.x] += t;
        __syncthreads();
    }
    if (i < N) offs[i] = sh[threadIdx.x] - v;   // exclusive
    if (threadIdx.x == 1023) partials[blockIdx.x] = sh[1023];
}

__global__ void k_scan2(int* __restrict__ partials, int nb)
{
    if (threadIdx.x == 0 && blockIdx.x == 0) {
        int run = 0;
        for (int k = 0; k < nb; k++) { int t = partials[k]; partials[k] = run; run += t; }
    }
}

__global__ __launch_bounds__(1024) void k_scan3(
    int* __restrict__ offs, const int* __restrict__ partials, int* __restrict__ cursor, int N)
{
    int i = blockIdx.x * 1024 + threadIdx.x;
    if (i < N) {
        int o = offs[i] + partials[blockIdx.x];
        offs[i] = o;
        cursor[i] = o;
    }
}

__global__ __launch_bounds__(256) void k_scatter(
    const int* __restrict__ ei, int* __restrict__ cursor,
    int* __restrict__ src_sorted, int* __restrict__ eid_sorted, int E, int N)
{
    int e = blockIdx.x * 256 + threadIdx.x;
    if (e >= E + N) return;
    int src, dst;
    if (e < E) { src = ei[e]; dst = ei[E + e]; }
    else       { src = e - E; dst = src; }
    int pos = atomicAdd(&cursor[dst], 1);
    src_sorted[pos] = src;
    eid_sorted[pos] = e;
}

// ---------- K_fused: per-node online-softmax score + aggregate (1 wave / node) ----------
__global__ __launch_bounds__(256) void k_fused(
    const int* __restrict__ src_sorted, const int* __restrict__ eid_sorted,
    const int* __restrict__ offs, const int* __restrict__ counts,
    const u16* __restrict__ xl, const u16* __restrict__ xr, const float* __restrict__ att,
    float* __restrict__ e_buf, float* __restrict__ m_buf, float* __restrict__ s_buf,
    float* __restrict__ out_mean, int N)
{
    int wid = (blockIdx.x * 256 + threadIdx.x) >> 6;
    int lane = threadIdx.x & 63;
    if (wid >= N) return;
    const int node = wid;

    uint4 b = ((const uint4*)(xr + (size_t)node * HC))[lane];
    float xrv[8] = { bflo(b.x), bfhi(b.x), bflo(b.y), bfhi(b.y),
                     bflo(b.z), bfhi(b.z), bflo(b.w), bfhi(b.w) };
    float4 w0 = ((const float4*)att)[lane * 2];
    float4 w1 = ((const float4*)att)[lane * 2 + 1];
    float wv[8] = { w0.x, w0.y, w0.z, w0.w, w1.x, w1.y, w1.z, w1.w };

    float m = -3.402823466e38f, s = 0.f;
    float acc[8] = {0, 0, 0, 0, 0, 0, 0, 0};

    const int beg = offs[node];
    const int deg = counts[node];

    for (int base = 0; base < deg; base += 64) {
        int cnt = min(64, deg - base);
        int my_src = 0, my_eid = 0;
        if (lane < cnt) {
            my_src = src_sorted[beg + base + lane];
            my_eid = eid_sorted[beg + base + lane];
        }
        int s0 = __shfl(my_src, 0);
        uint4 a = ((const uint4*)(xl + (size_t)s0 * HC))[lane];
        for (int t = 0; t < cnt; t++) {
            uint4 ac = a;
            if (t + 1 < cnt) {   // prefetch next row
                int sn = __shfl(my_src, t + 1);
                a = ((const uint4*)(xl + (size_t)sn * HC))[lane];
            }
            float xv[8] = { bflo(ac.x), bfhi(ac.x), bflo(ac.y), bfhi(ac.y),
                            bflo(ac.z), bfhi(ac.z), bflo(ac.w), bfhi(ac.w) };
            float esum = 0.f;
            #pragma unroll
            for (int q = 0; q < 8; q++) {
                float v = xv[q] + xrv[q];
                v = v > 0.f ? v : 0.2f * v;      // leaky_relu
                esum += v * wv[q];
            }
            esum += __shfl_xor(esum, 1);
            esum += __shfl_xor(esum, 2);         // all 4 lanes of head group hold e

            int eid = __shfl(my_eid, t);
            if ((lane & 3) == 0)
                e_buf[(size_t)eid * HH + (lane >> 2)] = esum;

            float mn = fmaxf(m, esum);
            float sc = __expf(m - mn);
            float p  = __expf(esum - mn);
            s = s * sc + p;
            m = mn;
            #pragma unroll
            for (int q = 0; q < 8; q++) acc[q] = acc[q] * sc + p * xv[q];
        }
    }

    if ((lane & 3) == 0) {
        m_buf[(size_t)node * HH + (lane >> 2)] = m;
        s_buf[(size_t)node * HH + (lane >> 2)] = s;
    }
    float inv = 1.f / (s + 1e-16f);
    #pragma unroll
    for (int q = 0; q < 8; q++) acc[q] *= inv;
    #pragma unroll
    for (int st = 4; st <= 32; st <<= 1) {
        #pragma unroll
        for (int q = 0; q < 8; q++) acc[q] += __shfl_xor(acc[q], st);
    }
    if (lane < 4) {
        float* dp = out_mean + (size_t)node * CC + lane * 8;
        #pragma unroll
        for (int q = 0; q < 8; q++) dp[q] = acc[q];
    }
}

// ---------- K_alpha ----------
__global__ __launch_bounds__(256) void k_alpha(
    const int* __restrict__ ei, const float* __restrict__ e_buf,
    const float* __restrict__ m_buf, const float* __restrict__ s_buf,
    float* __restrict__ alpha_out, int E, int N)
{
    long long i = (long long)blockIdx.x * 256 + threadIdx.x;
    long long tot = (long long)(E + N) * HH;
    if (i >= tot) return;
    int edge = (int)(i >> 4);
    int h = (int)(i & 15);
    int dst = (edge < E) ? ei[E + edge] : edge - E;
    float m = m_buf[(size_t)dst * HH + h];
    float s = s_buf[(size_t)dst * HH + h];
    alpha_out[i] = __expf(e_buf[i] - m) / (s + 1e-16f);
}

// ---------- K_final ----------
__global__ __launch_bounds__(256) void k_final(
    const float* __restrict__ out_mean, const float* __restrict__ xres,
    const float* __restrict__ bias, float* __restrict__ x_out, int N)
{
    int i = blockIdx.x * 256 + threadIdx.x;
    if (i >= N * CC) return;
    int c = i & 31;
    float g = out_mean[i] * (1.f / 16.f) + bias[c];
    g = g > 0.f ? g : 0.f;
    x_out[i] = g + xres[i];
}

extern "C" void kernel_launch(void* const* d_in, const int* in_sizes, int n_in,
                              void* d_out, int out_size, void* d_ws, size_t ws_size,
                              hipStream_t stream)
{
    const int N = in_sizes[0] / KIN;   // 50000
    const int E = in_sizes[1] / 2;     // 400000
    const int Etot = E + N;

    const float* x    = (const float*)d_in[0];
    const int*   ei   = (const int*)d_in[1];
    const float* Wl   = (const float*)d_in[4];
    const float* Wr   = (const float*)d_in[5];
    const float* att  = (const float*)d_in[6];
    const float* bias = (const float*)d_in[7];
    const float* Wres = (const float*)d_in[8];

    char* ws = (char*)d_ws;
    u16*   xl         = (u16*)ws;   ws += (size_t)N * HC * 2;
    u16*   xr         = (u16*)ws;   ws += (size_t)N * HC * 2;
    float* e_buf      = (float*)ws; ws += (size_t)Etot * HH * 4;
    float* m_buf      = (float*)ws; ws += (size_t)N * HH * 4;
    float* s_buf      = (float*)ws; ws += (size_t)N * HH * 4;
    float* xres       = (float*)ws; ws += (size_t)N * CC * 4;
    float* out_mean   = (float*)ws; ws += (size_t)N * CC * 4;
    int*   counts     = (int*)ws;   ws += (size_t)N * 4;
    int*   offs       = (int*)ws;   ws += (size_t)N * 4;
    int*   cursor     = (int*)ws;   ws += (size_t)N * 4;
    int*   partials   = (int*)ws;   ws += 256;
    int*   src_sorted = (int*)ws;   ws += (size_t)Etot * 4;
    int*   eid_sorted = (int*)ws;   ws += (size_t)Etot * 4;
    u16*   xb         = (u16*)ws;   ws += (size_t)N * KIN * 2;
    u16*   wbt        = (u16*)ws;   ws += (size_t)CT * KIN * 2;

    float* x_out     = (float*)d_out;
    float* alpha_out = x_out + (size_t)N * CC;

    hipMemsetAsync(counts, 0, (size_t)N * 4, stream);

    int xtot = N * KIN;
    k_xconv<<<(xtot / 8 + 255) / 256, 256, 0, stream>>>(x, xb, xtot);
    k_wconv<<<CT, 128, 0, stream>>>(Wl, Wr, Wres, wbt);
    k_mfma<<<dim3((N + 127) / 128, 9), 256, 0, stream>>>(xb, wbt, xl, xr, xres, N);

    int eg = (Etot + 255) / 256;
    k_count<<<eg, 256, 0, stream>>>(ei, counts, E, N);

    int nb = (N + 1023) / 1024;
    k_scan1<<<nb, 1024, 0, stream>>>(counts, offs, partials, N);
    k_scan2<<<1, 64, 0, stream>>>(partials, nb);
    k_scan3<<<nb, 1024, 0, stream>>>(offs, partials, cursor, N);

    k_scatter<<<eg, 256, 0, stream>>>(ei, cursor, src_sorted, eid_sorted, E, N);

    k_fused<<<(N * 64 + 255) / 256, 256, 0, stream>>>(
        src_sorted, eid_sorted, offs, counts, xl, xr, att,
        e_buf, m_buf, s_buf, out_mean, N);

    int ag = (int)(((long long)Etot * HH + 255) / 256);
    k_alpha<<<ag, 256, 0, stream>>>(ei, e_buf, m_buf, s_buf, alpha_out, E, N);

    k_final<<<(N * CC + 255) / 256, 256, 0, stream>>>(out_mean, xres, bias, x_out, N);
}

// Round 5
// 247.641 us; speedup vs baseline: 3.3079x; 1.0447x over previous
//
#include <hip/hip_runtime.h>
#include <hip/hip_bf16.h>

typedef unsigned int u32;
typedef unsigned short u16;

typedef __attribute__((ext_vector_type(8))) short bf16x8;
typedef __attribute__((ext_vector_type(4))) float f32x4;

// ---------- bf16 helpers ----------
__device__ __forceinline__ float bflo(u32 p){ union{u32 u; float f;} v; v.u = p << 16; return v.f; }
__device__ __forceinline__ float bfhi(u32 p){ union{u32 u; float f;} v; v.u = p & 0xFFFF0000u; return v.f; }
__device__ __forceinline__ u16 f2bf(float f){
    union{float f; u32 u;} v; v.f = f;
    u32 r = (v.u + 0x7FFFu + ((v.u >> 16) & 1u)) >> 16;
    return (u16)r;
}
__device__ __forceinline__ u32 pack2(float a, float b){
    return ((u32)f2bf(a)) | (((u32)f2bf(b)) << 16);
}

#define HH 16
#define CC 32
#define HC 512   // H*C
#define KIN 128
#define CT 1056  // 512 + 512 + 32 output cols
#define RESCALE_THR 8.0f

// ---------- K_xconv: x fp32 -> bf16 (packed) ----------
__global__ __launch_bounds__(256) void k_xconv(
    const float* __restrict__ x, u16* __restrict__ xb, int total)
{
    int t = blockIdx.x * 256 + threadIdx.x;   // one thread = 8 floats
    if (t * 8 >= total) return;
    const float4* src = (const float4*)(x + (size_t)t * 8);
    float4 a = src[0], b = src[1];
    uint4 o;
    o.x = pack2(a.x, a.y); o.y = pack2(a.z, a.w);
    o.z = pack2(b.x, b.y); o.w = pack2(b.z, b.w);
    ((uint4*)xb)[t] = o;
}

// ---------- K_wconv: W fp32 [128][cols] -> wbt bf16 [1056][128] (transposed) ----------
__global__ __launch_bounds__(128) void k_wconv(
    const float* __restrict__ Wl, const float* __restrict__ Wr,
    const float* __restrict__ Wres, u16* __restrict__ wbt)
{
    int c = blockIdx.x;        // 0..1055
    int k = threadIdx.x;       // 0..127
    float v;
    if (c < 512)       v = Wl[(size_t)k * 512 + c];
    else if (c < 1024) v = Wr[(size_t)k * 512 + (c - 512)];
    else               v = Wres[(size_t)k * 32 + (c - 1024)];
    wbt[(size_t)c * 128 + k] = f2bf(v);
}

// ---------- K_mfma: [M,128] x [128,1056] via mfma_f32_16x16x32_bf16 ----------
// XCD-aware 1D grid: row-block rb handled entirely by XCD rb%8 so all 9
// col-blocks of rb share the same L2 (xb row-slice reused 9x from L2).
__global__ __launch_bounds__(256) void k_mfma(
    const u16* __restrict__ xb, const u16* __restrict__ wbt,
    u16* __restrict__ xl, u16* __restrict__ xr, float* __restrict__ xres,
    int N, int nrb)
{
    __shared__ u16 As[128 * 128];   // 32 KB
    const int i = blockIdx.x;
    const int xcd = i & 7;
    const int j = i >> 3;
    const int rb = xcd + 8 * (j / 9);
    const int cb = j % 9;
    if (rb >= nrb) return;
    const int tid = threadIdx.x;
    const int wave = tid >> 6, lane = tid & 63;
    const int row0 = rb * 128;
    const int col0 = cb * 128;
    const int nct = (cb == 8) ? 2 : 8;   // cb==8 -> xres (32 cols)

    // stage A: thread i handles 16B chunk (row i>>4, chunk i&15), XOR swizzle
    uint4 zero = {0, 0, 0, 0};
    #pragma unroll
    for (int it = 0; it < 8; it++) {
        int idx = tid + it * 256;        // 0..2047
        int r = idx >> 4, ch = idx & 15;
        int grow = row0 + r;
        uint4 v = (grow < N) ? ((const uint4*)(xb + (size_t)grow * KIN))[ch] : zero;
        *(uint4*)(As + r * 128 + ((ch ^ (r & 7)) * 8)) = v;
    }
    __syncthreads();

    // A fragments: lane&15 -> row, (lane>>4)*8 -> k offset within K=32 step
    bf16x8 afrag[2][4];
    #pragma unroll
    for (int mt = 0; mt < 2; mt++) {
        #pragma unroll
        for (int kk = 0; kk < 4; kk++) {
            int r = wave * 32 + mt * 16 + (lane & 15);
            int chunk = (kk * 4 + (lane >> 4)) ^ (r & 7);
            afrag[mt][kk] = *(const bf16x8*)(As + r * 128 + chunk * 8);
        }
    }

    #pragma unroll
    for (int nt = 0; nt < 8; nt++) {
        if (nt < nct) {
            int col = col0 + nt * 16 + (lane & 15);
            const uint4* bp = (const uint4*)(wbt + (size_t)col * KIN);
            bf16x8 bfrag[4];
            #pragma unroll
            for (int kk = 0; kk < 4; kk++) {
                union { uint4 u; bf16x8 v; } cv;
                cv.u = bp[kk * 4 + (lane >> 4)];
                bfrag[kk] = cv.v;
            }
            f32x4 acc0 = {0, 0, 0, 0}, acc1 = {0, 0, 0, 0};
            #pragma unroll
            for (int kk = 0; kk < 4; kk++) {
                acc0 = __builtin_amdgcn_mfma_f32_16x16x32_bf16(afrag[0][kk], bfrag[kk], acc0, 0, 0, 0);
                acc1 = __builtin_amdgcn_mfma_f32_16x16x32_bf16(afrag[1][kk], bfrag[kk], acc1, 0, 0, 0);
            }
            // C/D: col = lane&15, row = (lane>>4)*4 + j
            int c_all = col0 + nt * 16 + (lane & 15);
            #pragma unroll
            for (int mt = 0; mt < 2; mt++) {
                f32x4 a = (mt == 0) ? acc0 : acc1;
                int rbse = row0 + wave * 32 + mt * 16 + (lane >> 4) * 4;
                #pragma unroll
                for (int jj = 0; jj < 4; jj++) {
                    int grow = rbse + jj;
                    if (grow < N) {
                        float v = a[jj];
                        if (c_all < 512)       xl[(size_t)grow * HC + c_all] = f2bf(v);
                        else if (c_all < 1024) xr[(size_t)grow * HC + (c_all - 512)] = f2bf(v);
                        else                   xres[(size_t)grow * CC + (c_all - 1024)] = v;
                    }
                }
            }
        }
    }
}

// ---------- CSR build ----------
__global__ __launch_bounds__(256) void k_count(
    const int* __restrict__ ei, int* __restrict__ counts, int E, int N)
{
    int e = blockIdx.x * 256 + threadIdx.x;
    if (e >= E + N) return;
    int dst = (e < E) ? ei[E + e] : e - E;
    atomicAdd(&counts[dst], 1);
}

__global__ __launch_bounds__(1024) void k_scan1(
    const int* __restrict__ counts, int* __restrict__ offs, int* __restrict__ partials, int N)
{
    __shared__ int sh[1024];
    int i = blockIdx.x * 1024 + threadIdx.x;
    int v = (i < N) ? counts[i] : 0;
    sh[threadIdx.x] = v;
    __syncthreads();
    for (int off = 1; off < 1024; off <<= 1) {
        int t = (threadIdx.x >= off) ? sh[threadIdx.x - off] : 0;
        __syncthreads();
        sh[threadIdx.x] += t;
        __syncthreads();
    }
    if (i < N) offs[i] = sh[threadIdx.x] - v;   // exclusive
    if (threadIdx.x == 1023) partials[blockIdx.x] = sh[1023];
}

__global__ void k_scan2(int* __restrict__ partials, int nb)
{
    if (threadIdx.x == 0 && blockIdx.x == 0) {
        int run = 0;
        for (int k = 0; k < nb; k++) { int t = partials[k]; partials[k] = run; run += t; }
    }
}

__global__ __launch_bounds__(1024) void k_scan3(
    int* __restrict__ offs, const int* __restrict__ partials, int* __restrict__ cursor, int N)
{
    int i = blockIdx.x * 1024 + threadIdx.x;
    if (i < N) {
        int o = offs[i] + partials[blockIdx.x];
        offs[i] = o;
        cursor[i] = o;
    }
}

__global__ __launch_bounds__(256) void k_scatter(
    const int* __restrict__ ei, int* __restrict__ cursor,
    int* __restrict__ src_sorted, int* __restrict__ eid_sorted, int E, int N)
{
    int e = blockIdx.x * 256 + threadIdx.x;
    if (e >= E + N) return;
    int src, dst;
    if (e < E) { src = ei[e]; dst = ei[E + e]; }
    else       { src = e - E; dst = src; }
    int pos = atomicAdd(&cursor[dst], 1);
    src_sorted[pos] = src;
    eid_sorted[pos] = e;
}

// ---------- K_fused: per-node online-softmax score + aggregate + alpha ----------
// 1 wave/node. Pass 1: online softmax with defer-rescale (THR=8), raw e -> e_buf.
// Pass 2: alpha = exp(e - m)/s written straight to alpha_out (final m,s in regs).
__global__ __launch_bounds__(256) void k_fused(
    const int* __restrict__ src_sorted, const int* __restrict__ eid_sorted,
    const int* __restrict__ offs, const int* __restrict__ counts,
    const u16* __restrict__ xl, const u16* __restrict__ xr, const float* __restrict__ att,
    float* __restrict__ e_buf, float* __restrict__ alpha_out,
    float* __restrict__ out_mean, int N)
{
    int wid = (blockIdx.x * 256 + threadIdx.x) >> 6;
    int lane = threadIdx.x & 63;
    if (wid >= N) return;
    const int node = wid;

    uint4 b = ((const uint4*)(xr + (size_t)node * HC))[lane];
    float xrv[8] = { bflo(b.x), bfhi(b.x), bflo(b.y), bfhi(b.y),
                     bflo(b.z), bfhi(b.z), bflo(b.w), bfhi(b.w) };
    float4 w0 = ((const float4*)att)[lane * 2];
    float4 w1 = ((const float4*)att)[lane * 2 + 1];
    float wv[8] = { w0.x, w0.y, w0.z, w0.w, w1.x, w1.y, w1.z, w1.w };

    float m = -3.402823466e38f, s = 0.f;
    float acc[8] = {0, 0, 0, 0, 0, 0, 0, 0};

    const int beg = offs[node];
    const int deg = counts[node];

    for (int base = 0; base < deg; base += 64) {
        int cnt = min(64, deg - base);
        int my_src = 0, my_eid = 0;
        if (lane < cnt) {
            my_src = src_sorted[beg + base + lane];
            my_eid = eid_sorted[beg + base + lane];
        }
        int s0 = __shfl(my_src, 0);
        uint4 a = ((const uint4*)(xl + (size_t)s0 * HC))[lane];
        for (int t = 0; t < cnt; t++) {
            uint4 ac = a;
            if (t + 1 < cnt) {   // prefetch next row
                int sn = __shfl(my_src, t + 1);
                a = ((const uint4*)(xl + (size_t)sn * HC))[lane];
            }
            float xv[8] = { bflo(ac.x), bfhi(ac.x), bflo(ac.y), bfhi(ac.y),
                            bflo(ac.z), bfhi(ac.z), bflo(ac.w), bfhi(ac.w) };
            float esum = 0.f;
            #pragma unroll
            for (int q = 0; q < 8; q++) {
                float v = xv[q] + xrv[q];
                v = fmaxf(v, 0.2f * v);          // leaky_relu (2 ops)
                esum = fmaf(v, wv[q], esum);
            }
            esum += __shfl_xor(esum, 1);
            esum += __shfl_xor(esum, 2);         // all 4 lanes of head group hold e

            int eid = __shfl(my_eid, t);
            if ((lane & 3) == 0)
                e_buf[(size_t)eid * HH + (lane >> 2)] = esum;

            if (__any(esum > m + RESCALE_THR)) {   // rare: rescale path
                float mn = fmaxf(m, esum);
                float sc = __expf(m - mn);
                float p  = __expf(esum - mn);
                s = s * sc + p;
                m = mn;
                #pragma unroll
                for (int q = 0; q < 8; q++) acc[q] = acc[q] * sc + p * xv[q];
            } else {                               // common: no rescale
                float p = __expf(esum - m);
                s += p;
                #pragma unroll
                for (int q = 0; q < 8; q++) acc[q] = fmaf(p, xv[q], acc[q]);
            }
        }
    }

    float inv = 1.f / (s + 1e-16f);

    // ---- pass 2: alpha finalize (4 edges/iter, lane&15 -> head) ----
    float m_h   = __shfl(m,   (lane & 15) * 4);
    float inv_h = __shfl(inv, (lane & 15) * 4);
    __threadfence_block();   // drain e_buf stores before reload
    for (int base = 0; base < deg; base += 4) {
        int t = base + (lane >> 4);
        if (t < deg) {
            int eid = eid_sorted[beg + t];
            float e = e_buf[(size_t)eid * HH + (lane & 15)];
            alpha_out[(size_t)eid * HH + (lane & 15)] = __expf(e - m_h) * inv_h;
        }
    }

    // ---- out_mean: scale + head reduction ----
    #pragma unroll
    for (int q = 0; q < 8; q++) acc[q] *= inv;
    #pragma unroll
    for (int st = 4; st <= 32; st <<= 1) {
        #pragma unroll
        for (int q = 0; q < 8; q++) acc[q] += __shfl_xor(acc[q], st);
    }
    if (lane < 4) {
        float* dp = out_mean + (size_t)node * CC + lane * 8;
        #pragma unroll
        for (int q = 0; q < 8; q++) dp[q] = acc[q];
    }
}

// ---------- K_final ----------
__global__ __launch_bounds__(256) void k_final(
    const float* __restrict__ out_mean, const float* __restrict__ xres,
    const float* __restrict__ bias, float* __restrict__ x_out, int N)
{
    int i = blockIdx.x * 256 + threadIdx.x;
    if (i >= N * CC) return;
    int c = i & 31;
    float g = out_mean[i] * (1.f / 16.f) + bias[c];
    g = g > 0.f ? g : 0.f;
    x_out[i] = g + xres[i];
}

extern "C" void kernel_launch(void* const* d_in, const int* in_sizes, int n_in,
                              void* d_out, int out_size, void* d_ws, size_t ws_size,
                              hipStream_t stream)
{
    const int N = in_sizes[0] / KIN;   // 50000
    const int E = in_sizes[1] / 2;     // 400000
    const int Etot = E + N;

    const float* x    = (const float*)d_in[0];
    const int*   ei   = (const int*)d_in[1];
    const float* Wl   = (const float*)d_in[4];
    const float* Wr   = (const float*)d_in[5];
    const float* att  = (const float*)d_in[6];
    const float* bias = (const float*)d_in[7];
    const float* Wres = (const float*)d_in[8];

    char* ws = (char*)d_ws;
    u16*   xl         = (u16*)ws;   ws += (size_t)N * HC * 2;
    u16*   xr         = (u16*)ws;   ws += (size_t)N * HC * 2;
    float* e_buf      = (float*)ws; ws += (size_t)Etot * HH * 4;
    float* xres       = (float*)ws; ws += (size_t)N * CC * 4;
    float* out_mean   = (float*)ws; ws += (size_t)N * CC * 4;
    int*   counts     = (int*)ws;   ws += (size_t)N * 4;
    int*   offs       = (int*)ws;   ws += (size_t)N * 4;
    int*   cursor     = (int*)ws;   ws += (size_t)N * 4;
    int*   partials   = (int*)ws;   ws += 256;
    int*   src_sorted = (int*)ws;   ws += (size_t)Etot * 4;
    int*   eid_sorted = (int*)ws;   ws += (size_t)Etot * 4;
    u16*   xb         = (u16*)ws;   ws += (size_t)N * KIN * 2;
    u16*   wbt        = (u16*)ws;   ws += (size_t)CT * KIN * 2;

    float* x_out     = (float*)d_out;
    float* alpha_out = x_out + (size_t)N * CC;

    hipMemsetAsync(counts, 0, (size_t)N * 4, stream);

    int xtot = N * KIN;
    k_xconv<<<(xtot / 8 + 255) / 256, 256, 0, stream>>>(x, xb, xtot);
    k_wconv<<<CT, 128, 0, stream>>>(Wl, Wr, Wres, wbt);

    int nrb = (N + 127) / 128;
    int mgrid = 8 * ((nrb + 7) / 8) * 9;
    k_mfma<<<mgrid, 256, 0, stream>>>(xb, wbt, xl, xr, xres, N, nrb);

    int eg = (Etot + 255) / 256;
    k_count<<<eg, 256, 0, stream>>>(ei, counts, E, N);

    int nb = (N + 1023) / 1024;
    k_scan1<<<nb, 1024, 0, stream>>>(counts, offs, partials, N);
    k_scan2<<<1, 64, 0, stream>>>(partials, nb);
    k_scan3<<<nb, 1024, 0, stream>>>(offs, partials, cursor, N);

    k_scatter<<<eg, 256, 0, stream>>>(ei, cursor, src_sorted, eid_sorted, E, N);

    k_fused<<<(N * 64 + 255) / 256, 256, 0, stream>>>(
        src_sorted, eid_sorted, offs, counts, xl, xr, att,
        e_buf, alpha_out, out_mean, N);

    k_final<<<(N * CC + 255) / 256, 256, 0, stream>>>(out_mean, xres, bias, x_out, N);
}